// Round 1
// baseline (126.492 us; speedup 1.0000x reference)
//
#include <hip/hip_runtime.h>
#include <hip/hip_bf16.h>

#define BATCH 8192
#define DMODEL 4096
#define NEXP 64

// ---------------- GEMM: logits[b][e] = sum_k x[b][k] * W[e][k] ----------------
// tile: 64 rows x 64 experts, BK=32, 256 threads (16x16, 4x4 register block),
// optional split-K over gridDim.y (NS template param).
template<int NS>
__global__ __launch_bounds__(256) void gemm_kernel(const float* __restrict__ x,
                                                   const float* __restrict__ W,
                                                   float* __restrict__ dst)
{
    // transposed tiles: As[k][r], Bs[k][e], stride 68 (16B-aligned rows, pads banks)
    __shared__ float As[32 * 68];
    __shared__ float Bs[32 * 68];

    const int t = threadIdx.x;
    const int rbase = blockIdx.x * 64;
    const int kbeg = blockIdx.y * (DMODEL / NS);
    const int kend = kbeg + (DMODEL / NS);

    const int ty = t >> 4;      // 0..15 -> rows ty*4..ty*4+3
    const int tx = t & 15;      // 0..15 -> experts tx*4..tx*4+3
    const int qs = t & 7;       // k-slot for staging (8 slots * 4 floats = 32 k)
    const int rr0 = t >> 3;     // 0..31  row/expert for staging

    float acc[4][4] = {};

    for (int kc = kbeg; kc < kend; kc += 32) {
        __syncthreads();
        // ---- stage A: x[rbase..rbase+63][kc..kc+31] -> As[k][r]
        {
            const float4 v0 = *reinterpret_cast<const float4*>(&x[(size_t)(rbase + rr0) * DMODEL + kc + qs * 4]);
            const float4 v1 = *reinterpret_cast<const float4*>(&x[(size_t)(rbase + rr0 + 32) * DMODEL + kc + qs * 4]);
            As[(qs * 4 + 0) * 68 + rr0] = v0.x;
            As[(qs * 4 + 1) * 68 + rr0] = v0.y;
            As[(qs * 4 + 2) * 68 + rr0] = v0.z;
            As[(qs * 4 + 3) * 68 + rr0] = v0.w;
            As[(qs * 4 + 0) * 68 + rr0 + 32] = v1.x;
            As[(qs * 4 + 1) * 68 + rr0 + 32] = v1.y;
            As[(qs * 4 + 2) * 68 + rr0 + 32] = v1.z;
            As[(qs * 4 + 3) * 68 + rr0 + 32] = v1.w;
        }
        // ---- stage B: W[0..63][kc..kc+31] -> Bs[k][e]
        {
            const float4 v0 = *reinterpret_cast<const float4*>(&W[(size_t)rr0 * DMODEL + kc + qs * 4]);
            const float4 v1 = *reinterpret_cast<const float4*>(&W[(size_t)(rr0 + 32) * DMODEL + kc + qs * 4]);
            Bs[(qs * 4 + 0) * 68 + rr0] = v0.x;
            Bs[(qs * 4 + 1) * 68 + rr0] = v0.y;
            Bs[(qs * 4 + 2) * 68 + rr0] = v0.z;
            Bs[(qs * 4 + 3) * 68 + rr0] = v0.w;
            Bs[(qs * 4 + 0) * 68 + rr0 + 32] = v1.x;
            Bs[(qs * 4 + 1) * 68 + rr0 + 32] = v1.y;
            Bs[(qs * 4 + 2) * 68 + rr0 + 32] = v1.z;
            Bs[(qs * 4 + 3) * 68 + rr0 + 32] = v1.w;
        }
        __syncthreads();

        // ---- compute
#pragma unroll
        for (int k = 0; k < 32; ++k) {
            const float4 a = *reinterpret_cast<const float4*>(&As[k * 68 + ty * 4]);
            const float4 b = *reinterpret_cast<const float4*>(&Bs[k * 68 + tx * 4]);
            const float av[4] = {a.x, a.y, a.z, a.w};
            const float bv[4] = {b.x, b.y, b.z, b.w};
#pragma unroll
            for (int i = 0; i < 4; ++i)
#pragma unroll
                for (int j = 0; j < 4; ++j)
                    acc[i][j] += av[i] * bv[j];
        }
    }

    // ---- write result
#pragma unroll
    for (int i = 0; i < 4; ++i) {
        const int row = rbase + ty * 4 + i;
        float4 v = make_float4(acc[i][0], acc[i][1], acc[i][2], acc[i][3]);
        if (NS == 1) {
            *reinterpret_cast<float4*>(&dst[(size_t)row * NEXP + tx * 4]) = v;
        } else {
            *reinterpret_cast<float4*>(&dst[((size_t)blockIdx.y * BATCH + row) * NEXP + tx * 4]) = v;
        }
    }
}

// ---------------- Router: top-2, softmax weights, full softmax accumulation ----------------
__global__ __launch_bounds__(256) void router_kernel(const float* __restrict__ part,
                                                     const float* __restrict__ logits_io,
                                                     const float* __restrict__ noise,
                                                     float* __restrict__ out,
                                                     float* __restrict__ probsum,
                                                     float* __restrict__ counts,
                                                     int ns)
{
    __shared__ float sps[4][64];
    __shared__ float scnt[4][64];

    const int t = threadIdx.x;
    const int w = t >> 6;
    const int lane = t & 63;
    const int wg = blockIdx.x * 4 + w;   // 0..1023

    float* out_idx = out;                 // [8192][2] as float
    float* out_w = out + 16384;           // [8192][2]
    float* out_logits = out + 32768;      // [8192][64]

    float psum_local = 0.f;
    float cnt_local = 0.f;

    for (int r = 0; r < 8; ++r) {
        const int row = wg * 8 + r;
        float l;
        if (ns == 2) {
            l = part[(size_t)row * NEXP + lane] + part[((size_t)BATCH + row) * NEXP + lane];
            out_logits[(size_t)row * NEXP + lane] = l;
        } else {
            l = logits_io[(size_t)row * NEXP + lane];
        }
        const float ny = l + 0.1f * noise[(size_t)row * NEXP + lane];

        // top-1 (value, index), tie -> lower index
        float v1 = ny; int i1 = lane;
#pragma unroll
        for (int m = 32; m >= 1; m >>= 1) {
            float ov = __shfl_xor(v1, m);
            int oi = __shfl_xor(i1, m);
            if (ov > v1 || (ov == v1 && oi < i1)) { v1 = ov; i1 = oi; }
        }
        // top-2: mask out winner
        float v2 = (lane == i1) ? -1e30f : ny; int i2 = lane;
#pragma unroll
        for (int m = 32; m >= 1; m >>= 1) {
            float ov = __shfl_xor(v2, m);
            int oi = __shfl_xor(i2, m);
            if (ov > v2 || (ov == v2 && oi < i2)) { v2 = ov; i2 = oi; }
        }

        if (lane == 0) {
            const float d = expf(v2 - v1);      // v1 >= v2
            const float w1 = 1.0f / (1.0f + d);
            out_idx[row * 2 + 0] = (float)i1;
            out_idx[row * 2 + 1] = (float)i2;
            out_w[row * 2 + 0] = w1;
            out_w[row * 2 + 1] = 1.0f - w1;
        }

        // full softmax over clean logits
        float m = l;
#pragma unroll
        for (int s = 32; s >= 1; s >>= 1) m = fmaxf(m, __shfl_xor(m, s));
        const float p = expf(l - m);
        float sum = p;
#pragma unroll
        for (int s = 32; s >= 1; s >>= 1) sum += __shfl_xor(sum, s);
        psum_local += p / sum;
        cnt_local += (lane == i1 ? 1.f : 0.f) + (lane == i2 ? 1.f : 0.f);
    }

    sps[w][lane] = psum_local;
    scnt[w][lane] = cnt_local;
    __syncthreads();
    if (t < 64) {
        float s = 0.f, c = 0.f;
#pragma unroll
        for (int ww = 0; ww < 4; ++ww) { s += sps[ww][t]; c += scnt[ww][t]; }
        atomicAdd(&probsum[t], s);
        atomicAdd(&counts[t], c);
    }
}

// ---------------- Loss ----------------
__global__ void loss_kernel(const float* __restrict__ probsum,
                            const float* __restrict__ counts,
                            float* __restrict__ out_loss)
{
    const int e = threadIdx.x;
    float v = probsum[e] * counts[e];
#pragma unroll
    for (int s = 32; s >= 1; s >>= 1) v += __shfl_xor(v, s);
    if (e == 0) {
        out_loss[0] = (float)NEXP * v / ((float)BATCH * (float)BATCH);
    }
}

extern "C" void kernel_launch(void* const* d_in, const int* in_sizes, int n_in,
                              void* d_out, int out_size, void* d_ws, size_t ws_size,
                              hipStream_t stream)
{
    const float* x = (const float*)d_in[0];
    const float* W = (const float*)d_in[1];
    const float* noise = (const float*)d_in[2];
    float* out = (float*)d_out;
    float* ws = (float*)d_ws;

    float* probsum = ws;            // 64 floats
    float* counts = ws + 64;        // 64 floats
    float* partials = ws + 256;     // offset 1024 B: [2][8192][64] floats if split

    const size_t need_split = 1024 + (size_t)2 * BATCH * NEXP * sizeof(float);
    const int ns = (ws_size >= need_split) ? 2 : 1;

    float* out_logits = out + 32768;

    hipMemsetAsync(d_ws, 0, 512, stream);

    if (ns == 2) {
        gemm_kernel<2><<<dim3(128, 2), 256, 0, stream>>>(x, W, partials);
    } else {
        gemm_kernel<1><<<dim3(128, 1), 256, 0, stream>>>(x, W, out_logits);
    }

    router_kernel<<<256, 256, 0, stream>>>(partials, out_logits, noise, out, probsum, counts, ns);

    loss_kernel<<<1, 64, 0, stream>>>(probsum, counts, out + 557056);
}